// Round 5
// baseline (502.235 us; speedup 1.0000x reference)
//
#include <hip/hip_runtime.h>
#include <hip/hip_bf16.h>
#include <cstdint>

#define B_   4
#define S_   2048
#define E_   2048
#define H_   16
#define HKV_ 4
#define D_   128
#define KVD_ 512          // HKV_*D_
#define NQKV 3072         // E_ + 2*KVD_
// softmax scale folded into Q at projection time, in base-2 units:
// 1/sqrt(128) * log2(e)
#define QSCALE 0.1275253129f

typedef __bf16 bf16x8_t __attribute__((ext_vector_type(8)));
typedef float  f32x4_t  __attribute__((ext_vector_type(4)));
typedef float  f32x16_t __attribute__((ext_vector_type(16)));

__device__ __forceinline__ ushort f2bf(float f) {
  uint32_t u = __builtin_bit_cast(uint32_t, f);
  uint32_t r = u + 0x7FFFu + ((u >> 16) & 1u);   // round-to-nearest-even
  return (ushort)(r >> 16);
}

__device__ __forceinline__ void gload16(const void* g, void* l) {
  __builtin_amdgcn_global_load_lds(
      (__attribute__((address_space(1))) void*)g,
      (__attribute__((address_space(3))) void*)l, 16, 0, 0);
}

__device__ __forceinline__ uint32_t cvtpk(float lo, float hi) {
  uint32_t r;
  asm volatile("v_cvt_pk_bf16_f32 %0, %1, %2" : "=v"(r) : "v"(lo), "v"(hi));
  return r;
}

__device__ __forceinline__ void plswap(uint32_t& a, uint32_t& b) {
  asm volatile("v_permlane32_swap_b32 %0, %1" : "+v"(a), "+v"(b));
}

// ---------------- x -> bf16 ----------------
__global__ __launch_bounds__(256) void k_cvt_x(const float* __restrict__ x,
                                               ushort* __restrict__ xb) {
  int i = blockIdx.x * 256 + threadIdx.x;          // 8 floats per thread
  const float4* p = (const float4*)x + (size_t)i * 2;
  float4 a = p[0], b = p[1];
  uint4 o;
  o.x = (uint32_t)f2bf(a.x) | ((uint32_t)f2bf(a.y) << 16);
  o.y = (uint32_t)f2bf(a.z) | ((uint32_t)f2bf(a.w) << 16);
  o.z = (uint32_t)f2bf(b.x) | ((uint32_t)f2bf(b.y) << 16);
  o.w = (uint32_t)f2bf(b.z) | ((uint32_t)f2bf(b.w) << 16);
  ((uint4*)xb)[i] = o;
}

// ------------- weight -> bf16, transposed: wb[n][k] = w[k][n] -------------
__global__ __launch_bounds__(256) void k_cvt_w_t(const float* __restrict__ w,
                                                 ushort* __restrict__ wb,
                                                 int C, int n_off) {
  __shared__ ushort t[32][33];
  int c0 = blockIdx.x * 32, r0 = blockIdx.y * 32;
  int tx = threadIdx.x, ty = threadIdx.y;          // 32 x 8
#pragma unroll
  for (int i = 0; i < 4; ++i) {
    int r = ty + i * 8;
    t[r][tx] = f2bf(w[(size_t)(r0 + r) * C + c0 + tx]);
  }
  __syncthreads();
#pragma unroll
  for (int i = 0; i < 4; ++i) {
    int c = ty + i * 8;
    wb[(size_t)(n_off + c0 + c) * E_ + r0 + tx] = t[tx][c];
  }
}

// ------------- fused QKV projection GEMM ------------------------------------
// C[8192][3072] = xb[8192][2048] @ wb^T.
// BM=256, BN=128, BK=32; 4 waves (2M x 2N), per-wave 128x64 (acc 8x4 f32x4).
// TRIPLE-buffered LDS (72KB) -> 2 blocks/CU for cross-block desync overlap.
// Grid 768 = 3.0 exact rounds on 256 CUs. Prefetch distance 2 tiles;
// one counted vmcnt(6) per K-tile (drain only at tail).
// Half-tiles: A-half 128x32 (8KB, 2 gload16/thr), B-half 64x32 (4KB, 1).
// Swizzle: 16B chunk c ^= (row>>1)&3 (row stride 64B), both sides.
__global__ __launch_bounds__(256, 2) void k_gemm(
    const ushort* __restrict__ xb, const ushort* __restrict__ wb,
    const float* __restrict__ wq_b, const float* __restrict__ wk_b,
    const float* __restrict__ wv_b, const float* __restrict__ pos,
    ushort* __restrict__ qkv) {
  __shared__ char ldsb[3][24576];   // per buf: A 16KB @0 (2 halves), B 8KB @16384
  int tid = threadIdx.x, wid = tid >> 6, lane = tid & 63;
  int l15 = lane & 15, l4 = lane >> 4;
  int wm = wid >> 1, wn = wid & 1;

  // XCD swizzle (768 = 8 * 96, bijective); tm-fast within an XCD chunk
  int bid = blockIdx.x;
  bid = (bid & 7) * 96 + (bid >> 3);
  int tm = bid & 31, tn = bid >> 5;
  int m0 = tm * 256, n0 = tn * 128;

#define STAGE_A(TILE, MH, BUF)                                                 \
  {                                                                            \
    char* sb_ = ldsb[BUF] + (MH) * 8192;                                       \
    _Pragma("unroll") for (int i_ = 0; i_ < 2; ++i_) {                         \
      int u_ = i_ * 256 + tid;                                                 \
      int r_ = u_ >> 2;                                                        \
      int cs_ = (u_ & 3) ^ ((r_ >> 1) & 3);                                    \
      gload16(xb + (size_t)(m0 + (MH) * 128 + r_) * E_ + (TILE) * 32 + cs_ * 8,\
              sb_ + u_ * 16);                                                  \
    }                                                                          \
  }
#define STAGE_B(TILE, NH, BUF)                                                 \
  {                                                                            \
    char* sb_ = ldsb[BUF] + 16384 + (NH) * 4096;                               \
    int r_ = tid >> 2;                                                         \
    int cs_ = (tid & 3) ^ ((r_ >> 1) & 3);                                     \
    gload16(wb + (size_t)(n0 + (NH) * 64 + r_) * E_ + (TILE) * 32 + cs_ * 8,   \
            sb_ + tid * 16);                                                   \
  }
#define READ_A(DST, RH, BUF)                                                   \
  _Pragma("unroll") for (int mi_ = 0; mi_ < 4; ++mi_) {                        \
    int lr_ = (RH) * 64 + mi_ * 16 + l15;                                      \
    int c_ = l4 ^ ((lr_ >> 1) & 3);                                            \
    DST[mi_] = *(const bf16x8_t*)(ldsb[BUF] + wm * 8192 + lr_ * 64 + c_ * 16); \
  }
#define READ_B(DST, PH, BUF)                                                   \
  _Pragma("unroll") for (int ni_ = 0; ni_ < 2; ++ni_) {                        \
    int lr_ = (PH) * 32 + ni_ * 16 + l15;                                      \
    int c_ = l4 ^ ((lr_ >> 1) & 3);                                            \
    DST[ni_] = *(const bf16x8_t*)(ldsb[BUF] + 16384 + wn * 4096 + lr_ * 64 +   \
                                  c_ * 16);                                    \
  }
#define MFMA8(RH, PH, AF, BF)                                                  \
  __builtin_amdgcn_s_setprio(1);                                               \
  _Pragma("unroll") for (int mi_ = 0; mi_ < 4; ++mi_)                          \
  _Pragma("unroll") for (int ni_ = 0; ni_ < 2; ++ni_)                          \
    acc[(RH) * 4 + mi_][(PH) * 2 + ni_] =                                      \
        __builtin_amdgcn_mfma_f32_16x16x32_bf16(                               \
            AF[mi_], BF[ni_], acc[(RH) * 4 + mi_][(PH) * 2 + ni_], 0, 0, 0);   \
  __builtin_amdgcn_s_setprio(0);
#define LGKM0()                                                                \
  asm volatile("s_waitcnt lgkmcnt(0)" ::: "memory");                           \
  __builtin_amdgcn_sched_barrier(0);
#define BAR() __builtin_amdgcn_s_barrier();

  f32x4_t acc[8][4] = {};

  const int NT = E_ / 32;   // 64 K-tiles
  // prologue: tiles 0 and 1, 6 loads each (A0 A1 B0 B1 order)
  STAGE_A(0, 0, 0); STAGE_A(0, 1, 0); STAGE_B(0, 0, 0); STAGE_B(0, 1, 0);
  STAGE_A(1, 0, 1); STAGE_A(1, 1, 1); STAGE_B(1, 0, 1); STAGE_B(1, 1, 1);
  asm volatile("s_waitcnt vmcnt(6)" ::: "memory");   // tile-0's 6 loads landed
  BAR();

  int rb = 0, sb = 2;   // read buffer (t%3), stage buffer ((t+2)%3)
  for (int t = 0; t < NT; ++t) {
    bf16x8_t af[4], b0[2], b1[2];
    bool pf = (t < NT - 2);

    // ---- ph0: rows 0-63 x B-half0 ----
    READ_A(af, 0, rb);
    READ_B(b0, 0, rb);
    if (pf) STAGE_A(t + 2, 0, sb);
    BAR(); LGKM0();
    MFMA8(0, 0, af, b0);
    BAR();

    // ---- ph1: rows 0-63 x B-half1 ----
    READ_B(b1, 1, rb);
    if (pf) STAGE_A(t + 2, 1, sb);
    BAR(); LGKM0();
    MFMA8(0, 1, af, b1);
    BAR();

    // ---- ph2: rows 64-127 x B-half0 ----
    READ_A(af, 1, rb);
    if (pf) STAGE_B(t + 2, 0, sb);
    BAR(); LGKM0();
    MFMA8(1, 0, af, b0);
    BAR();

    // ---- ph3: rows 64-127 x B-half1 ----
    if (pf) STAGE_B(t + 2, 1, sb);
    BAR();
    MFMA8(1, 1, af, b1);
    // tile-end: next tile's 6 loads must have landed
    if (pf) { asm volatile("s_waitcnt vmcnt(6)" ::: "memory"); }
    else    { asm volatile("s_waitcnt vmcnt(0)" ::: "memory"); }
    BAR();

    rb = (rb == 2) ? 0 : rb + 1;
    sb = (sb == 2) ? 0 : sb + 1;
  }

  // epilogue: +bias, +pos (Q,K), *QSCALE (Q), -> bf16
#pragma unroll
  for (int mi = 0; mi < 8; ++mi) {
#pragma unroll
    for (int ni = 0; ni < 4; ++ni) {
      int n = n0 + wn * 64 + ni * 16 + l15;
      int mbase = m0 + wm * 128 + mi * 16 + l4 * 4;
#pragma unroll
      for (int r = 0; r < 4; ++r) {
        int m = mbase + r;
        int srow = m & (S_ - 1);
        float v = acc[mi][ni][r];
        if (n < E_)
          v = (v + wq_b[n] + pos[(size_t)srow * E_ + n]) * QSCALE;
        else if (n < E_ + KVD_)
          v = v + wk_b[n - E_] + pos[(size_t)srow * E_ + (n - E_)];
        else
          v = v + wv_b[n - E_ - KVD_];
        qkv[(size_t)m * NQKV + n] = f2bf(v);
      }
    }
  }
#undef STAGE_A
#undef STAGE_B
#undef READ_A
#undef READ_B
#undef MFMA8
#undef LGKM0
#undef BAR
}

// ------------- V transpose: vt[(b*4+kh)*128 + d][s] = V[b][s][kh][d] -------------
__global__ __launch_bounds__(256) void k_v_t(const ushort* __restrict__ qkv,
                                             ushort* __restrict__ vt) {
  __shared__ ushort t[32][33];
  int b = blockIdx.z >> 2, kh = blockIdx.z & 3;
  int s0 = blockIdx.x * 32, d0 = blockIdx.y * 32;
  int tx = threadIdx.x, ty = threadIdx.y;
#pragma unroll
  for (int i = 0; i < 4; ++i) {
    int s = s0 + ty + i * 8;
    t[ty + i * 8][tx] =
        qkv[(size_t)(b * S_ + s) * NQKV + E_ + KVD_ + kh * D_ + d0 + tx];
  }
  __syncthreads();
#pragma unroll
  for (int i = 0; i < 4; ++i) {
    int d = d0 + ty + i * 8;
    vt[(size_t)((b * HKV_ + kh) * D_ + d) * S_ + s0 + tx] = t[tx][ty + i * 8];
  }
}

// ------------- flash attention: m214-style 8-wave 32x32 swapped-QK -------------
__global__ __launch_bounds__(512, 2) void k_attn(const ushort* __restrict__ qkv,
                                                 const ushort* __restrict__ vt,
                                                 float* __restrict__ out) {
  __shared__ char lds[2][32768];   // per buf: Ks 16KB @0, Vs 16KB @16384
  int tid = threadIdx.x, wid = tid >> 6, lane = tid & 63;
  int l31 = lane & 31, hi = lane >> 5;
  int bh = blockIdx.y;
  int b = bh >> 4, h = bh & 15, kh = h >> 2;
  int qw0 = blockIdx.x * 256 + wid * 32;

  bf16x8_t qf[8];
  {
    const ushort* qg = qkv + (size_t)(b * S_ + qw0 + l31) * NQKV + h * D_ + hi * 8;
#pragma unroll
    for (int k = 0; k < 8; ++k) qf[k] = *(const bf16x8_t*)(qg + k * 16);
  }

  const ushort* kbase = qkv + (size_t)b * S_ * NQKV + E_ + kh * D_;
  const ushort* vbase = vt + (size_t)(b * HKV_ + kh) * D_ * S_;

  int rk0 = wid * 4 + (lane >> 4);
  int dk0 = ((lane & 15) * 8);
  int dv0 = wid * 8 + (lane >> 3);
  int kv0 = ((lane & 7) * 8);

  f32x16_t ao[4] = {};
  float mrow = -1e30f, lsum = 0.f;

#define STAGE(key0, bufp)                                                      \
  {                                                                            \
    char* bp_ = (bufp);                                                        \
    _Pragma("unroll")                                                          \
    for (int i = 0; i < 2; ++i) {                                              \
      int rk = i * 32 + rk0;                                                   \
      int dk = dk0 ^ ((rk & 7) << 3);                                          \
      gload16(kbase + (size_t)((key0) + rk) * NQKV + dk,                       \
              bp_ + i * 8192 + wid * 1024);                                    \
      int dv = i * 64 + dv0;                                                   \
      int kv = kv0 ^ ((dv & 7) << 3);                                          \
      gload16(vbase + (size_t)dv * S_ + (key0) + kv,                           \
              bp_ + 16384 + i * 8192 + wid * 1024);                            \
    }                                                                          \
  }

  STAGE(0, lds[0]);
  __syncthreads();

  int cur = 0;
  const int nt = S_ / 64;
  for (int t = 0; t < nt; ++t) {
    if (t + 1 < nt) STAGE((t + 1) * 64, lds[cur ^ 1]);

    const ushort* Ks = (const ushort*)(lds[cur]);
    const ushort* Vs = (const ushort*)(lds[cur] + 16384);

    f32x16_t sc[2] = {};
#pragma unroll
    for (int kb = 0; kb < 2; ++kb) {
      int row = kb * 32 + l31;
      const ushort* kr = Ks + row * 128;
      int sw = (l31 & 7) << 3;
#pragma unroll
      for (int ks = 0; ks < 8; ++ks) {
        bf16x8_t kf = *(const bf16x8_t*)(kr + ((ks * 16 + hi * 8) ^ sw));
        sc[kb] = __builtin_amdgcn_mfma_f32_32x32x16_bf16(kf, qf[ks], sc[kb], 0, 0, 0);
      }
    }

    float tmax = sc[0][0];
#pragma unroll
    for (int r = 1; r < 16; ++r) tmax = fmaxf(tmax, sc[0][r]);
#pragma unroll
    for (int r = 0; r < 16; ++r) tmax = fmaxf(tmax, sc[1][r]);
    tmax = fmaxf(tmax, __shfl_xor(tmax, 32));

    if (!__all(tmax - mrow <= 8.f)) {
      float mnew = fmaxf(mrow, tmax);
      float f = __builtin_amdgcn_exp2f(mrow - mnew);
      mrow = mnew;
      lsum *= f;
#pragma unroll
      for (int r = 0; r < 16; ++r) {
        float fr = __shfl(f, (r & 3) + 8 * (r >> 2) + 4 * hi);
        ao[0][r] *= fr; ao[1][r] *= fr; ao[2][r] *= fr; ao[3][r] *= fr;
      }
    }

    float rs = 0.f;
#pragma unroll
    for (int kb = 0; kb < 2; ++kb)
#pragma unroll
      for (int r = 0; r < 16; ++r) {
        float p = __builtin_amdgcn_exp2f(sc[kb][r] - mrow);
        sc[kb][r] = p;
        rs += p;
      }
    rs += __shfl_xor(rs, 32);
    lsum += rs;

    bf16x8_t pa[4];
#pragma unroll
    for (int kb = 0; kb < 2; ++kb) {
      uint32_t c0 = cvtpk(sc[kb][0], sc[kb][1]);
      uint32_t c1 = cvtpk(sc[kb][2], sc[kb][3]);
      uint32_t c2 = cvtpk(sc[kb][4], sc[kb][5]);
      uint32_t c3 = cvtpk(sc[kb][6], sc[kb][7]);
      uint32_t c4 = cvtpk(sc[kb][8], sc[kb][9]);
      uint32_t c5 = cvtpk(sc[kb][10], sc[kb][11]);
      uint32_t c6 = cvtpk(sc[kb][12], sc[kb][13]);
      uint32_t c7 = cvtpk(sc[kb][14], sc[kb][15]);
      plswap(c0, c2); plswap(c1, c3); plswap(c4, c6); plswap(c5, c7);
      uint4 u0 = {c0, c1, c2, c3};
      uint4 u1 = {c4, c5, c6, c7};
      pa[kb * 2]     = __builtin_bit_cast(bf16x8_t, u0);
      pa[kb * 2 + 1] = __builtin_bit_cast(bf16x8_t, u1);
    }

#pragma unroll
    for (int dblk = 0; dblk < 4; ++dblk) {
      int row = dblk * 32 + l31;
      const ushort* vr = Vs + row * 64;
      int sw = (l31 & 7) << 3;
#pragma unroll
      for (int ks = 0; ks < 4; ++ks) {
        bf16x8_t vf = *(const bf16x8_t*)(vr + ((ks * 16 + hi * 8) ^ sw));
        ao[dblk] = __builtin_amdgcn_mfma_f32_32x32x16_bf16(pa[ks], vf, ao[dblk], 0, 0, 0);
      }
    }

    __syncthreads();
    cur ^= 1;
  }

  float rinv = 1.0f / lsum;
#pragma unroll
  for (int r = 0; r < 16; ++r) {
    float rv = __shfl(rinv, (r & 3) + 8 * (r >> 2) + 4 * hi);
    int q = qw0 + (r & 3) + 8 * (r >> 2) + 4 * hi;
    float* og = out + (size_t)(b * S_ + q) * E_ + h * D_ + l31;
#pragma unroll
    for (int dblk = 0; dblk < 4; ++dblk)
      og[dblk * 32] = ao[dblk][r] * rv;
  }
#undef STAGE
}

extern "C" void kernel_launch(void* const* d_in, const int* in_sizes, int n_in,
                              void* d_out, int out_size, void* d_ws, size_t ws_size,
                              hipStream_t stream) {
  const float* x    = (const float*)d_in[0];
  const float* wq_w = (const float*)d_in[1];
  const float* wq_b = (const float*)d_in[2];
  const float* wk_w = (const float*)d_in[3];
  const float* wk_b = (const float*)d_in[4];
  const float* wv_w = (const float*)d_in[5];
  const float* wv_b = (const float*)d_in[6];
  const float* pos  = (const float*)d_in[7];
  float* out = (float*)d_out;

  ushort* xb  = (ushort*)d_out;                          // 33.5 MB
  ushort* wb  = (ushort*)((char*)d_out + 33554432);      // 12.6 MB
  ushort* qkv = (ushort*)d_ws;                           // 50.3 MB
  ushort* vt  = (ushort*)((char*)d_ws + 50331648);       // 8.4 MB

  k_cvt_x<<<dim3((B_ * S_ * E_) / 8 / 256), 256, 0, stream>>>(x, xb);
  dim3 tb(32, 8);
  k_cvt_w_t<<<dim3(E_ / 32, E_ / 32), tb, 0, stream>>>(wq_w, wb, E_, 0);
  k_cvt_w_t<<<dim3(KVD_ / 32, E_ / 32), tb, 0, stream>>>(wk_w, wb, KVD_, E_);
  k_cvt_w_t<<<dim3(KVD_ / 32, E_ / 32), tb, 0, stream>>>(wv_w, wb, KVD_, E_ + KVD_);
  k_gemm<<<dim3(768), 256, 0, stream>>>(xb, wb, wq_b, wk_b, wv_b, pos, qkv);
  k_v_t<<<dim3(S_ / 32, D_ / 32, B_ * HKV_), tb, 0, stream>>>(qkv, vt);
  k_attn<<<dim3(S_ / 256, B_ * H_), 512, 0, stream>>>(qkv, vt, out);
}

// Round 6
// 489.815 us; speedup vs baseline: 1.0254x; 1.0254x over previous
//
#include <hip/hip_runtime.h>
#include <hip/hip_bf16.h>
#include <cstdint>

#define B_   4
#define S_   2048
#define E_   2048
#define H_   16
#define HKV_ 4
#define D_   128
#define KVD_ 512          // HKV_*D_
#define NQKV 3072         // E_ + 2*KVD_
// softmax scale folded into Q at projection time, in base-2 units:
// 1/sqrt(128) * log2(e)
#define QSCALE 0.1275253129f

typedef __bf16 bf16x8_t __attribute__((ext_vector_type(8)));
typedef float  f32x4_t  __attribute__((ext_vector_type(4)));
typedef float  f32x16_t __attribute__((ext_vector_type(16)));

__device__ __forceinline__ ushort f2bf(float f) {
  uint32_t u = __builtin_bit_cast(uint32_t, f);
  uint32_t r = u + 0x7FFFu + ((u >> 16) & 1u);   // round-to-nearest-even
  return (ushort)(r >> 16);
}

__device__ __forceinline__ void gload16(const void* g, void* l) {
  __builtin_amdgcn_global_load_lds(
      (__attribute__((address_space(1))) void*)g,
      (__attribute__((address_space(3))) void*)l, 16, 0, 0);
}

__device__ __forceinline__ uint32_t cvtpk(float lo, float hi) {
  uint32_t r;
  asm volatile("v_cvt_pk_bf16_f32 %0, %1, %2" : "=v"(r) : "v"(lo), "v"(hi));
  return r;
}

__device__ __forceinline__ void plswap(uint32_t& a, uint32_t& b) {
  asm volatile("v_permlane32_swap_b32 %0, %1" : "+v"(a), "+v"(b));
}

// ---------------- x -> bf16 ----------------
__global__ __launch_bounds__(256) void k_cvt_x(const float* __restrict__ x,
                                               ushort* __restrict__ xb) {
  int i = blockIdx.x * 256 + threadIdx.x;          // 8 floats per thread
  const float4* p = (const float4*)x + (size_t)i * 2;
  float4 a = p[0], b = p[1];
  uint4 o;
  o.x = (uint32_t)f2bf(a.x) | ((uint32_t)f2bf(a.y) << 16);
  o.y = (uint32_t)f2bf(a.z) | ((uint32_t)f2bf(a.w) << 16);
  o.z = (uint32_t)f2bf(b.x) | ((uint32_t)f2bf(b.y) << 16);
  o.w = (uint32_t)f2bf(b.z) | ((uint32_t)f2bf(b.w) << 16);
  ((uint4*)xb)[i] = o;
}

// ------------- weight -> bf16, transposed: wb[n][k] = w[k][n] -------------
__global__ __launch_bounds__(256) void k_cvt_w_t(const float* __restrict__ w,
                                                 ushort* __restrict__ wb,
                                                 int C, int n_off) {
  __shared__ ushort t[32][33];
  int c0 = blockIdx.x * 32, r0 = blockIdx.y * 32;
  int tx = threadIdx.x, ty = threadIdx.y;          // 32 x 8
#pragma unroll
  for (int i = 0; i < 4; ++i) {
    int r = ty + i * 8;
    t[r][tx] = f2bf(w[(size_t)(r0 + r) * C + c0 + tx]);
  }
  __syncthreads();
#pragma unroll
  for (int i = 0; i < 4; ++i) {
    int c = ty + i * 8;
    wb[(size_t)(n_off + c0 + c) * E_ + r0 + tx] = t[tx][c];
  }
}

// ------------- fused QKV projection GEMM: 256x256 8-phase (m201 template) ---
// C[8192][3072] = xb[8192][2048] @ wb^T.  BM=BN=256, BK=64, 8 waves (2Mx4N).
// LDS 128KB: A[buf][half] 4x16KB @0, B[buf][half] 4x16KB @64KB.
// Half-tile = 128 rows x 64 cols bf16, XOR-swizzled 16B chunks (chunk ^= row&7)
// via pre-swizzled global source (linear gload_lds dest).
// Counted vmcnt only (no lgkmcnt(0)/sched_barrier fences — the compiler
// emits precise lgkmcnt for its own ds_read->MFMA deps; explicit per-phase
// drains recreate m141's 510-TF order-pinning pathology).
__global__ __launch_bounds__(512, 2) void k_gemm(
    const ushort* __restrict__ xb, const ushort* __restrict__ wb,
    const float* __restrict__ wq_b, const float* __restrict__ wk_b,
    const float* __restrict__ wv_b, const float* __restrict__ pos,
    ushort* __restrict__ qkv) {
  __shared__ char ldsb[131072];
  int tid = threadIdx.x, wid = tid >> 6, lane = tid & 63;
  int l15 = lane & 15, l4 = lane >> 4;
  int wm = wid >> 2, wn = wid & 3;

  // XCD swizzle (384 = 8 * 48, bijective); tn-major chunks keep B-panel in L2
  int bid = blockIdx.x;
  bid = (bid & 7) * 48 + (bid >> 3);
  int tm = bid & 31, tn = bid >> 5;
  int m0 = tm * 256, n0 = tn * 256;

#define STAGE_A(TILE, MH)                                                      \
  {                                                                            \
    char* sb_ = ldsb + (((TILE)&1) * 32768) + ((MH) * 16384);                  \
    _Pragma("unroll") for (int i_ = 0; i_ < 2; ++i_) {                         \
      int s_ = i_ * 8 + wid;                                                   \
      int r_ = s_ * 8 + (lane >> 3);                                           \
      int cg_ = (lane & 7) ^ ((lane >> 3) & 7);                                \
      gload16(xb + (size_t)(m0 + (MH) * 128 + r_) * E_ + (TILE) * 64 + cg_ * 8,\
              sb_ + s_ * 1024);                                                \
    }                                                                          \
  }
#define STAGE_B(TILE, NH)                                                      \
  {                                                                            \
    char* sb_ = ldsb + 65536 + (((TILE)&1) * 32768) + ((NH) * 16384);          \
    _Pragma("unroll") for (int i_ = 0; i_ < 2; ++i_) {                         \
      int s_ = i_ * 8 + wid;                                                   \
      int r_ = s_ * 8 + (lane >> 3);                                           \
      int cg_ = (lane & 7) ^ ((lane >> 3) & 7);                                \
      gload16(wb + (size_t)(n0 + (NH) * 128 + r_) * E_ + (TILE) * 64 + cg_ * 8,\
              sb_ + s_ * 1024);                                                \
    }                                                                          \
  }
#define READ_A(DST, SLOT)                                                      \
  _Pragma("unroll") for (int mi_ = 0; mi_ < 4; ++mi_)                          \
  _Pragma("unroll") for (int kk_ = 0; kk_ < 2; ++kk_) {                        \
    int r_ = wm * 64 + mi_ * 16 + l15;                                         \
    int c_ = (kk_ * 4 + l4) ^ (r_ & 7);                                        \
    DST[mi_][kk_] = *(const bf16x8_t*)((SLOT) + r_ * 128 + c_ * 16);           \
  }
#define READ_B(DST, SLOT)                                                      \
  _Pragma("unroll") for (int ni_ = 0; ni_ < 2; ++ni_)                          \
  _Pragma("unroll") for (int kk_ = 0; kk_ < 2; ++kk_) {                        \
    int r_ = wn * 32 + ni_ * 16 + l15;                                         \
    int c_ = (kk_ * 4 + l4) ^ (r_ & 7);                                        \
    DST[ni_][kk_] = *(const bf16x8_t*)((SLOT) + r_ * 128 + c_ * 16);           \
  }
#define MFMA_QUAD(MH, NH, AF, BF)                                              \
  __builtin_amdgcn_s_setprio(1);                                               \
  _Pragma("unroll") for (int kk_ = 0; kk_ < 2; ++kk_)                          \
  _Pragma("unroll") for (int mi_ = 0; mi_ < 4; ++mi_)                          \
  _Pragma("unroll") for (int ni_ = 0; ni_ < 2; ++ni_)                          \
    acc[(MH) * 4 + mi_][(NH) * 2 + ni_] =                                      \
        __builtin_amdgcn_mfma_f32_16x16x32_bf16(                               \
            AF[mi_][kk_], BF[ni_][kk_], acc[(MH) * 4 + mi_][(NH) * 2 + ni_],   \
            0, 0, 0);                                                          \
  __builtin_amdgcn_s_setprio(0);
#define BAR() __builtin_amdgcn_s_barrier();

  f32x4_t acc[8][4] = {};

  const int NT = E_ / 64;   // 32
  // prologue: matches steady-state issue order; 6 half-tiles in flight
  STAGE_A(0, 0); STAGE_B(0, 0); STAGE_A(0, 1); STAGE_B(0, 1);
  STAGE_A(1, 0); STAGE_B(1, 0);
  asm volatile("s_waitcnt vmcnt(8)" ::: "memory");   // A0[0],B0[0] landed
  BAR();

  for (int t = 0; t < NT; ++t) {
    const char* Ab = ldsb + (t & 1) * 32768;
    const char* Bb = ldsb + 65536 + (t & 1) * 32768;
    bf16x8_t af[4][2], b0[2][2], b1[2][2];

    // ---- ph0: quadrant (0,0) ----
    READ_A(af, Ab);
    READ_B(b0, Bb);
    if (t + 1 < NT) STAGE_A(t + 1, 1);
    BAR();
    MFMA_QUAD(0, 0, af, b0);
    asm volatile("s_waitcnt vmcnt(6)" ::: "memory");  // B1[t],A1[t] landed
    BAR();

    // ---- ph1: quadrant (0,1) ----
    READ_B(b1, Bb + 16384);
    if (t + 1 < NT) STAGE_B(t + 1, 1);
    BAR();
    MFMA_QUAD(0, 1, af, b1);
    BAR();

    // ---- ph2: quadrant (1,0) ----
    READ_A(af, Ab + 16384);
    if (t + 2 < NT) STAGE_A(t + 2, 0);
    BAR();
    MFMA_QUAD(1, 0, af, b0);
    BAR();

    // ---- ph3: quadrant (1,1) ----
    if (t + 2 < NT) STAGE_B(t + 2, 0);
    BAR();
    MFMA_QUAD(1, 1, af, b1);
    asm volatile("s_waitcnt vmcnt(8)" ::: "memory");  // A0[t+1],B0[t+1] landed
    BAR();
  }

  // epilogue: +bias, +pos (Q,K), *QSCALE (Q), -> bf16
#pragma unroll
  for (int mh = 0; mh < 2; ++mh)
#pragma unroll
    for (int mi = 0; mi < 4; ++mi)
#pragma unroll
      for (int nh = 0; nh < 2; ++nh)
#pragma unroll
        for (int ni = 0; ni < 2; ++ni) {
          int n = n0 + nh * 128 + wn * 32 + ni * 16 + l15;
          int mbase = m0 + mh * 128 + wm * 64 + mi * 16 + l4 * 4;
#pragma unroll
          for (int r = 0; r < 4; ++r) {
            int m = mbase + r;
            int srow = m & (S_ - 1);
            float v = acc[mh * 4 + mi][nh * 2 + ni][r];
            if (n < E_)
              v = (v + wq_b[n] + pos[(size_t)srow * E_ + n]) * QSCALE;
            else if (n < E_ + KVD_)
              v = v + wk_b[n - E_] + pos[(size_t)srow * E_ + (n - E_)];
            else
              v = v + wv_b[n - E_ - KVD_];
            qkv[(size_t)m * NQKV + n] = f2bf(v);
          }
        }
#undef STAGE_A
#undef STAGE_B
#undef READ_A
#undef READ_B
#undef MFMA_QUAD
#undef BAR
}

// ------------- V transpose: vt[(b*4+kh)*128 + d][s] = V[b][s][kh][d] -------------
__global__ __launch_bounds__(256) void k_v_t(const ushort* __restrict__ qkv,
                                             ushort* __restrict__ vt) {
  __shared__ ushort t[32][33];
  int b = blockIdx.z >> 2, kh = blockIdx.z & 3;
  int s0 = blockIdx.x * 32, d0 = blockIdx.y * 32;
  int tx = threadIdx.x, ty = threadIdx.y;
#pragma unroll
  for (int i = 0; i < 4; ++i) {
    int s = s0 + ty + i * 8;
    t[ty + i * 8][tx] =
        qkv[(size_t)(b * S_ + s) * NQKV + E_ + KVD_ + kh * D_ + d0 + tx];
  }
  __syncthreads();
#pragma unroll
  for (int i = 0; i < 4; ++i) {
    int d = d0 + ty + i * 8;
    vt[(size_t)((b * HKV_ + kh) * D_ + d) * S_ + s0 + tx] = t[tx][ty + i * 8];
  }
}

// ------------- flash attention: m214-style 8-wave 32x32 swapped-QK -------------
__global__ __launch_bounds__(512, 2) void k_attn(const ushort* __restrict__ qkv,
                                                 const ushort* __restrict__ vt,
                                                 float* __restrict__ out) {
  __shared__ char lds[2][32768];   // per buf: Ks 16KB @0, Vs 16KB @16384
  int tid = threadIdx.x, wid = tid >> 6, lane = tid & 63;
  int l31 = lane & 31, hi = lane >> 5;
  int bh = blockIdx.y;
  int b = bh >> 4, h = bh & 15, kh = h >> 2;
  int qw0 = blockIdx.x * 256 + wid * 32;

  bf16x8_t qf[8];
  {
    const ushort* qg = qkv + (size_t)(b * S_ + qw0 + l31) * NQKV + h * D_ + hi * 8;
#pragma unroll
    for (int k = 0; k < 8; ++k) qf[k] = *(const bf16x8_t*)(qg + k * 16);
  }

  const ushort* kbase = qkv + (size_t)b * S_ * NQKV + E_ + kh * D_;
  const ushort* vbase = vt + (size_t)(b * HKV_ + kh) * D_ * S_;

  int rk0 = wid * 4 + (lane >> 4);
  int dk0 = ((lane & 15) * 8);
  int dv0 = wid * 8 + (lane >> 3);
  int kv0 = ((lane & 7) * 8);

  f32x16_t ao[4] = {};
  float mrow = -1e30f, lsum = 0.f;

#define STAGE(key0, bufp)                                                      \
  {                                                                            \
    char* bp_ = (bufp);                                                        \
    _Pragma("unroll")                                                          \
    for (int i = 0; i < 2; ++i) {                                              \
      int rk = i * 32 + rk0;                                                   \
      int dk = dk0 ^ ((rk & 7) << 3);                                          \
      gload16(kbase + (size_t)((key0) + rk) * NQKV + dk,                       \
              bp_ + i * 8192 + wid * 1024);                                    \
      int dv = i * 64 + dv0;                                                   \
      int kv = kv0 ^ ((dv & 7) << 3);                                          \
      gload16(vbase + (size_t)dv * S_ + (key0) + kv,                           \
              bp_ + 16384 + i * 8192 + wid * 1024);                            \
    }                                                                          \
  }

  STAGE(0, lds[0]);
  __syncthreads();

  int cur = 0;
  const int nt = S_ / 64;
  for (int t = 0; t < nt; ++t) {
    if (t + 1 < nt) STAGE((t + 1) * 64, lds[cur ^ 1]);

    const ushort* Ks = (const ushort*)(lds[cur]);
    const ushort* Vs = (const ushort*)(lds[cur] + 16384);

    f32x16_t sc[2] = {};
#pragma unroll
    for (int kb = 0; kb < 2; ++kb) {
      int row = kb * 32 + l31;
      const ushort* kr = Ks + row * 128;
      int sw = (l31 & 7) << 3;
#pragma unroll
      for (int ks = 0; ks < 8; ++ks) {
        bf16x8_t kf = *(const bf16x8_t*)(kr + ((ks * 16 + hi * 8) ^ sw));
        sc[kb] = __builtin_amdgcn_mfma_f32_32x32x16_bf16(kf, qf[ks], sc[kb], 0, 0, 0);
      }
    }

    float tmax = sc[0][0];
#pragma unroll
    for (int r = 1; r < 16; ++r) tmax = fmaxf(tmax, sc[0][r]);
#pragma unroll
    for (int r = 0; r < 16; ++r) tmax = fmaxf(tmax, sc[1][r]);
    tmax = fmaxf(tmax, __shfl_xor(tmax, 32));

    if (!__all(tmax - mrow <= 8.f)) {
      float mnew = fmaxf(mrow, tmax);
      float f = __builtin_amdgcn_exp2f(mrow - mnew);
      mrow = mnew;
      lsum *= f;
#pragma unroll
      for (int r = 0; r < 16; ++r) {
        float fr = __shfl(f, (r & 3) + 8 * (r >> 2) + 4 * hi);
        ao[0][r] *= fr; ao[1][r] *= fr; ao[2][r] *= fr; ao[3][r] *= fr;
      }
    }

    float rs = 0.f;
#pragma unroll
    for (int kb = 0; kb < 2; ++kb)
#pragma unroll
      for (int r = 0; r < 16; ++r) {
        float p = __builtin_amdgcn_exp2f(sc[kb][r] - mrow);
        sc[kb][r] = p;
        rs += p;
      }
    rs += __shfl_xor(rs, 32);
    lsum += rs;

    bf16x8_t pa[4];
#pragma unroll
    for (int kb = 0; kb < 2; ++kb) {
      uint32_t c0 = cvtpk(sc[kb][0], sc[kb][1]);
      uint32_t c1 = cvtpk(sc[kb][2], sc[kb][3]);
      uint32_t c2 = cvtpk(sc[kb][4], sc[kb][5]);
      uint32_t c3 = cvtpk(sc[kb][6], sc[kb][7]);
      uint32_t c4 = cvtpk(sc[kb][8], sc[kb][9]);
      uint32_t c5 = cvtpk(sc[kb][10], sc[kb][11]);
      uint32_t c6 = cvtpk(sc[kb][12], sc[kb][13]);
      uint32_t c7 = cvtpk(sc[kb][14], sc[kb][15]);
      plswap(c0, c2); plswap(c1, c3); plswap(c4, c6); plswap(c5, c7);
      uint4 u0 = {c0, c1, c2, c3};
      uint4 u1 = {c4, c5, c6, c7};
      pa[kb * 2]     = __builtin_bit_cast(bf16x8_t, u0);
      pa[kb * 2 + 1] = __builtin_bit_cast(bf16x8_t, u1);
    }

#pragma unroll
    for (int dblk = 0; dblk < 4; ++dblk) {
      int row = dblk * 32 + l31;
      const ushort* vr = Vs + row * 64;
      int sw = (l31 & 7) << 3;
#pragma unroll
      for (int ks = 0; ks < 4; ++ks) {
        bf16x8_t vf = *(const bf16x8_t*)(vr + ((ks * 16 + hi * 8) ^ sw));
        ao[dblk] = __builtin_amdgcn_mfma_f32_32x32x16_bf16(pa[ks], vf, ao[dblk], 0, 0, 0);
      }
    }

    __syncthreads();
    cur ^= 1;
  }

  float rinv = 1.0f / lsum;
#pragma unroll
  for (int r = 0; r < 16; ++r) {
    float rv = __shfl(rinv, (r & 3) + 8 * (r >> 2) + 4 * hi);
    int q = qw0 + (r & 3) + 8 * (r >> 2) + 4 * hi;
    float* og = out + (size_t)(b * S_ + q) * E_ + h * D_ + l31;
#pragma unroll
    for (int dblk = 0; dblk < 4; ++dblk)
      og[dblk * 32] = ao[dblk][r] * rv;
  }
#undef STAGE
}

extern "C" void kernel_launch(void* const* d_in, const int* in_sizes, int n_in,
                              void* d_out, int out_size, void* d_ws, size_t ws_size,
                              hipStream_t stream) {
  const float* x    = (const float*)d_in[0];
  const float* wq_w = (const float*)d_in[1];
  const float* wq_b = (const float*)d_in[2];
  const float* wk_w = (const float*)d_in[3];
  const float* wk_b = (const float*)d_in[4];
  const float* wv_w = (const float*)d_in[5];
  const float* wv_b = (const float*)d_in[6];
  const float* pos  = (const float*)d_in[7];
  float* out = (float*)d_out;

  ushort* xb  = (ushort*)d_out;                          // 33.5 MB
  ushort* wb  = (ushort*)((char*)d_out + 33554432);      // 12.6 MB
  ushort* qkv = (ushort*)d_ws;                           // 50.3 MB
  ushort* vt  = (ushort*)((char*)d_ws + 50331648);       // 8.4 MB

  k_cvt_x<<<dim3((B_ * S_ * E_) / 8 / 256), 256, 0, stream>>>(x, xb);
  dim3 tb(32, 8);
  k_cvt_w_t<<<dim3(E_ / 32, E_ / 32), tb, 0, stream>>>(wq_w, wb, E_, 0);
  k_cvt_w_t<<<dim3(KVD_ / 32, E_ / 32), tb, 0, stream>>>(wk_w, wb, KVD_, E_);
  k_cvt_w_t<<<dim3(KVD_ / 32, E_ / 32), tb, 0, stream>>>(wv_w, wb, KVD_, E_ + KVD_);
  k_gemm<<<dim3(384), 512, 0, stream>>>(xb, wb, wq_b, wk_b, wv_b, pos, qkv);
  k_v_t<<<dim3(S_ / 32, D_ / 32, B_ * HKV_), tb, 0, stream>>>(qkv, vt);
  k_attn<<<dim3(S_ / 256, B_ * H_), 512, 0, stream>>>(qkv, vt, out);
}